// Round 6
// baseline (640.569 us; speedup 1.0000x reference)
//
#include <hip/hip_runtime.h>
#include <math.h>

#define HID 64
#define NLAY 5
#define NFF 512

// Broadcast lane k's value to all 64 lanes via v_readlane (k is wave-uniform).
__device__ __forceinline__ float bcastf(float v, int lane) {
  return __int_as_float(__builtin_amdgcn_readlane(__float_as_int(v), lane));
}

// Wl[l] = edge_emb_w (4x64) @ edge_lin_w[l] (64x64)  -> [4][64] per layer
__global__ void prep_wl_kernel(const float* __restrict__ edge_emb_w,
                               const float* __restrict__ edge_lin_w,
                               float* __restrict__ Wl) {
  int l = blockIdx.x;
  int t = threadIdx.x;       // 256 threads = 4 j-rows x 64 dims
  int j = t >> 6;
  int d = t & 63;
  const float* ew = edge_emb_w + j * HID;
  const float* lw = edge_lin_w + l * HID * HID;
  float acc = 0.f;
#pragma unroll
  for (int k = 0; k < HID; ++k) acc = fmaf(ew[k], lw[k * HID + d], acc);
  Wl[(l * 4 + j) * HID + d] = acc;
}

// h[n][d] = vert_emb[x[n]][d]
__global__ void embed_kernel(const int* __restrict__ x,
                             const float* __restrict__ vert_emb,
                             float* __restrict__ h, int n) {
  int idx = blockIdx.x * blockDim.x + threadIdx.x;
  if (idx >= n * HID) return;
  int node = idx >> 6;
  int d = idx & 63;
  h[idx] = vert_emb[x[node] * HID + d];
}

// ---- CSR build (once per call, reused across 5 layers) ----

__global__ void zero_deg_kernel(int* __restrict__ deg, int n) {
  int i = blockIdx.x * blockDim.x + threadIdx.x;
  if (i < n) deg[i] = 0;
}

__global__ void hist_kernel(const int* __restrict__ dst, int* __restrict__ deg, int E) {
  int e = blockIdx.x * blockDim.x + threadIdx.x;
  if (e < E) atomicAdd(&deg[dst[e]], 1);
}

// Multi-block exclusive scan, phase 1: per-block sums.
__global__ void bsum_kernel(const int* __restrict__ deg, int* __restrict__ bsum, int n) {
  __shared__ int s[256];
  int t = threadIdx.x;
  int i = blockIdx.x * 256 + t;
  s[t] = (i < n) ? deg[i] : 0;
  __syncthreads();
#pragma unroll
  for (int off = 128; off > 0; off >>= 1) {
    if (t < off) s[t] += s[t + off];
    __syncthreads();
  }
  if (t == 0) bsum[blockIdx.x] = s[0];
}

// Phase 2: one block scans the block sums -> exclusive offsets.
__global__ void bscan_kernel(const int* __restrict__ bsum, int* __restrict__ boff, int nb) {
  __shared__ int s[256];
  int t = threadIdx.x;
  int v = (t < nb) ? bsum[t] : 0;
  s[t] = v;
  __syncthreads();
#pragma unroll
  for (int off = 1; off < 256; off <<= 1) {
    int u = (t >= off) ? s[t - off] : 0;
    __syncthreads();
    s[t] += u;
    __syncthreads();
  }
  if (t < nb) boff[t] = s[t] - v;   // exclusive
}

// Phase 3: per-block scan + offset -> row_ptr, cursor; last element writes row_ptr[n].
__global__ void scan3_kernel(const int* __restrict__ deg, const int* __restrict__ boff,
                             int* __restrict__ row_ptr, int* __restrict__ cursor, int n) {
  __shared__ int s[256];
  int t = threadIdx.x;
  int i = blockIdx.x * 256 + t;
  int v = (i < n) ? deg[i] : 0;
  s[t] = v;
  __syncthreads();
#pragma unroll
  for (int off = 1; off < 256; off <<= 1) {
    int u = (t >= off) ? s[t - off] : 0;
    __syncthreads();
    s[t] += u;
    __syncthreads();
  }
  if (i < n) {
    int excl = boff[blockIdx.x] + s[t] - v;
    row_ptr[i] = excl;
    cursor[i] = excl;
    if (i == n - 1) row_ptr[n] = excl + v;
  }
}

__global__ void scatter_kernel(const int* __restrict__ src,
                               const int* __restrict__ dst,
                               const float4* __restrict__ edge_attr,
                               int* __restrict__ cursor,
                               int* __restrict__ csr_src,
                               float4* __restrict__ csr_ea, int E) {
  int e = blockIdx.x * blockDim.x + threadIdx.x;
  if (e >= E) return;
  int pos = atomicAdd(&cursor[dst[e]], 1);
  csr_src[pos] = src[e];
  csr_ea[pos] = edge_attr[e];
}

// ---- gather: 1 wave per dst node, lane = dim, 8 loads in flight ----
// __launch_bounds__(256,8): cap 64 VGPR -> 8 waves/SIMD for max latency hiding.
__global__ __launch_bounds__(256, 8)
void gather_kernel(const int* __restrict__ row_ptr,
                   const int* __restrict__ csr_src,
                   const float4* __restrict__ csr_ea,
                   const float* __restrict__ Wl,   // [4][64]
                   const float* __restrict__ h,
                   float* __restrict__ agg, int n) {
  int wid = threadIdx.x >> 6;
  int d = threadIdx.x & 63;
  int node = blockIdx.x * 4 + wid;
  if (node >= n) return;
  int beg = __builtin_amdgcn_readfirstlane(row_ptr[node]);
  int end = __builtin_amdgcn_readfirstlane(row_ptr[node + 1]);
  float w0 = Wl[d], w1_ = Wl[HID + d], w2_ = Wl[2 * HID + d], w3_ = Wl[3 * HID + d];
  float acc = 0.f;
  int j = beg;
  for (; j + 8 <= end; j += 8) {
    int s0 = csr_src[j],     s1 = csr_src[j + 1], s2 = csr_src[j + 2], s3 = csr_src[j + 3];
    int s4 = csr_src[j + 4], s5 = csr_src[j + 5], s6 = csr_src[j + 6], s7 = csr_src[j + 7];
    float h0 = h[(size_t)s0 * HID + d];
    float h1 = h[(size_t)s1 * HID + d];
    float h2 = h[(size_t)s2 * HID + d];
    float h3 = h[(size_t)s3 * HID + d];
    float h4 = h[(size_t)s4 * HID + d];
    float h5 = h[(size_t)s5 * HID + d];
    float h6 = h[(size_t)s6 * HID + d];
    float h7 = h[(size_t)s7 * HID + d];
    float4 e0 = csr_ea[j],     e1 = csr_ea[j + 1], e2 = csr_ea[j + 2], e3 = csr_ea[j + 3];
    float4 e4 = csr_ea[j + 4], e5 = csr_ea[j + 5], e6 = csr_ea[j + 6], e7 = csr_ea[j + 7];
    float v0 = fmaf(e0.w, w3_, fmaf(e0.z, w2_, fmaf(e0.y, w1_, e0.x * w0)));
    float v1 = fmaf(e1.w, w3_, fmaf(e1.z, w2_, fmaf(e1.y, w1_, e1.x * w0)));
    float v2 = fmaf(e2.w, w3_, fmaf(e2.z, w2_, fmaf(e2.y, w1_, e2.x * w0)));
    float v3 = fmaf(e3.w, w3_, fmaf(e3.z, w2_, fmaf(e3.y, w1_, e3.x * w0)));
    float v4 = fmaf(e4.w, w3_, fmaf(e4.z, w2_, fmaf(e4.y, w1_, e4.x * w0)));
    float v5 = fmaf(e5.w, w3_, fmaf(e5.z, w2_, fmaf(e5.y, w1_, e5.x * w0)));
    float v6 = fmaf(e6.w, w3_, fmaf(e6.z, w2_, fmaf(e6.y, w1_, e6.x * w0)));
    float v7 = fmaf(e7.w, w3_, fmaf(e7.z, w2_, fmaf(e7.y, w1_, e7.x * w0)));
    acc = fmaf(h0, v0, acc); acc = fmaf(h1, v1, acc);
    acc = fmaf(h2, v2, acc); acc = fmaf(h3, v3, acc);
    acc = fmaf(h4, v4, acc); acc = fmaf(h5, v5, acc);
    acc = fmaf(h6, v6, acc); acc = fmaf(h7, v7, acc);
  }
  for (; j < end; ++j) {
    int s0 = csr_src[j];
    float4 e0 = csr_ea[j];
    float v0 = fmaf(e0.w, w3_, fmaf(e0.z, w2_, fmaf(e0.y, w1_, e0.x * w0)));
    acc = fmaf(h[(size_t)s0 * HID + d], v0, acc);
  }
  agg[(size_t)node * HID + d] = acc;
}

// hn = relu(agg@rel_w + rel_b + h@root_w) + h@res_w ; 8 nodes per wave.
__global__ __launch_bounds__(256, 4)
void node_kernel(const float* __restrict__ h,
                 const float* __restrict__ agg,
                 const float* __restrict__ rel_w,
                 const float* __restrict__ rel_b,
                 const float* __restrict__ root_w,
                 const float* __restrict__ res_w,
                 float* __restrict__ hn, int n) {
  int wid = threadIdx.x >> 6;
  int d = threadIdx.x & 63;
  int base = (blockIdx.x * 4 + wid) * 8;
  if (base >= n) return;
  float bd = rel_b[d];
  float hval[8], aval[8], acc2[8], accR[8];
#pragma unroll
  for (int i = 0; i < 8; ++i) {
    int node = base + i;
    bool ok = node < n;
    hval[i] = ok ? h[(size_t)node * HID + d] : 0.f;
    aval[i] = ok ? agg[(size_t)node * HID + d] : 0.f;
    acc2[i] = bd;
    accR[i] = 0.f;
  }
#pragma unroll 8
  for (int k = 0; k < HID; ++k) {
    float wr = rel_w[k * HID + d];
    float wo = root_w[k * HID + d];
    float wq = res_w[k * HID + d];
#pragma unroll
    for (int i = 0; i < 8; ++i) {
      float hk = bcastf(hval[i], k);
      float ak = bcastf(aval[i], k);
      acc2[i] = fmaf(ak, wr, acc2[i]);
      acc2[i] = fmaf(hk, wo, acc2[i]);
      accR[i] = fmaf(hk, wq, accR[i]);
    }
  }
#pragma unroll
  for (int i = 0; i < 8; ++i) {
    int node = base + i;
    if (node < n)
      hn[(size_t)node * HID + d] = fmaxf(acc2[i], 0.f) + accR[i];
  }
}

// out[n] = b2 + sum_f gelu(h[n]@w1[:,f] + b1[f]) * w2[f] ; 16 nodes per wave.
// 16 nodes/wave halves the per-wave full-w1 stream (128 KB) vs 8 nodes/wave.
// Feature mapping: f = lane*8 + c -> w1 row loads are two coalesced float4s.
__global__ __launch_bounds__(256, 2)
void head_kernel(const float* __restrict__ h,
                 const float4* __restrict__ w1v,  // [64][128] float4
                 const float4* __restrict__ b1v,  // [128] float4
                 const float4* __restrict__ w2v,  // [128] float4
                 const float* __restrict__ b2,
                 float* __restrict__ out, int n) {
  int wid = threadIdx.x >> 6;
  int lane = threadIdx.x & 63;
  int base = (blockIdx.x * 4 + wid) * 16;
  if (base >= n) return;
  float hval[16];
#pragma unroll
  for (int i = 0; i < 16; ++i)
    hval[i] = (base + i < n) ? h[(size_t)(base + i) * HID + lane] : 0.f;
  float acc[16][8];
#pragma unroll
  for (int i = 0; i < 16; ++i)
#pragma unroll
    for (int c = 0; c < 8; ++c) acc[i][c] = 0.f;
#pragma unroll 2
  for (int k = 0; k < HID; ++k) {
    float4 wa = w1v[k * (NFF / 4) + lane * 2];
    float4 wb = w1v[k * (NFF / 4) + lane * 2 + 1];
#pragma unroll
    for (int i = 0; i < 16; ++i) {
      float hk = bcastf(hval[i], k);
      acc[i][0] = fmaf(hk, wa.x, acc[i][0]);
      acc[i][1] = fmaf(hk, wa.y, acc[i][1]);
      acc[i][2] = fmaf(hk, wa.z, acc[i][2]);
      acc[i][3] = fmaf(hk, wa.w, acc[i][3]);
      acc[i][4] = fmaf(hk, wb.x, acc[i][4]);
      acc[i][5] = fmaf(hk, wb.y, acc[i][5]);
      acc[i][6] = fmaf(hk, wb.z, acc[i][6]);
      acc[i][7] = fmaf(hk, wb.w, acc[i][7]);
    }
  }
  float4 ba = b1v[lane * 2], bb = b1v[lane * 2 + 1];
  float4 va = w2v[lane * 2], vb = w2v[lane * 2 + 1];
  float bbuf[8] = {ba.x, ba.y, ba.z, ba.w, bb.x, bb.y, bb.z, bb.w};
  float wbuf[8] = {va.x, va.y, va.z, va.w, vb.x, vb.y, vb.z, vb.w};
  float partial[16];
#pragma unroll
  for (int i = 0; i < 16; ++i) partial[i] = 0.f;
#pragma unroll
  for (int c = 0; c < 8; ++c) {
#pragma unroll
    for (int i = 0; i < 16; ++i) {
      float xv = acc[i][c] + bbuf[c];
      float g = 0.5f * xv * (1.f + erff(xv * 0.70710678118654752f)); // exact GELU
      partial[i] = fmaf(g, wbuf[c], partial[i]);
    }
  }
#pragma unroll
  for (int i = 0; i < 16; ++i) {
#pragma unroll
    for (int off = 32; off > 0; off >>= 1)
      partial[i] += __shfl_xor(partial[i], off);
  }
  if (lane == 0) {
    float bias = b2[0];
#pragma unroll
    for (int i = 0; i < 16; ++i)
      if (base + i < n) out[base + i] = partial[i] + bias;
  }
}

extern "C" void kernel_launch(void* const* d_in, const int* in_sizes, int n_in,
                              void* d_out, int out_size, void* d_ws, size_t ws_size,
                              hipStream_t stream) {
  const int*   x          = (const int*)d_in[0];
  const int*   edge_index = (const int*)d_in[1];
  const float* edge_attr  = (const float*)d_in[2];
  const float* vert_emb   = (const float*)d_in[3];
  const float* edge_emb_w = (const float*)d_in[4];
  const float* edge_lin_w = (const float*)d_in[5];
  const float* rel_w      = (const float*)d_in[6];
  const float* rel_b      = (const float*)d_in[7];
  const float* root_w     = (const float*)d_in[8];
  const float* res_w      = (const float*)d_in[9];
  const float* w1         = (const float*)d_in[10];
  const float* b1         = (const float*)d_in[11];
  const float* w2         = (const float*)d_in[12];
  const float* b2         = (const float*)d_in[13];

  const int n = in_sizes[0];
  const int E = in_sizes[2] / 4;
  const int* src = edge_index;
  const int* dst = edge_index + E;
  const int nb = (n + 255) / 256;   // scan blocks (196 for n=50000)

  // workspace layout:
  //   Wl[2048] f | hA[n*64] f | hB[n*64] f | agg[n*64] f | csr_ea[E] float4 |
  //   csr_src[E] int | row_ptr[n+1] int | cursor[n] int | deg[n] int |
  //   bsum[256] int | boff[256] int
  float* ws   = (float*)d_ws;
  float* Wl   = ws;
  float* hA   = ws + 2048;
  float* hB   = hA + (size_t)n * HID;
  float* agg  = hB + (size_t)n * HID;
  float4* csr_ea = (float4*)(agg + (size_t)n * HID);
  int* csr_src = (int*)(csr_ea + (size_t)E);
  int* row_ptr = csr_src + E;
  int* cursor  = row_ptr + (n + 1);
  int* deg     = cursor + n;
  int* bsum    = deg + n;
  int* boff    = bsum + 256;

  prep_wl_kernel<<<dim3(NLAY), dim3(256), 0, stream>>>(edge_emb_w, edge_lin_w, Wl);

  int totalHD = n * HID;
  embed_kernel<<<dim3((totalHD + 255) / 256), dim3(256), 0, stream>>>(x, vert_emb, hA, n);

  // CSR build (amortized over 5 layers)
  zero_deg_kernel<<<dim3((n + 255) / 256), dim3(256), 0, stream>>>(deg, n);
  hist_kernel<<<dim3((E + 255) / 256), dim3(256), 0, stream>>>(dst, deg, E);
  bsum_kernel<<<dim3(nb), dim3(256), 0, stream>>>(deg, bsum, n);
  bscan_kernel<<<dim3(1), dim3(256), 0, stream>>>(bsum, boff, nb);
  scan3_kernel<<<dim3(nb), dim3(256), 0, stream>>>(deg, boff, row_ptr, cursor, n);
  scatter_kernel<<<dim3((E + 255) / 256), dim3(256), 0, stream>>>(
      src, dst, (const float4*)edge_attr, cursor, csr_src, csr_ea, E);

  float* hc = hA;
  float* hx = hB;
  for (int l = 0; l < NLAY; ++l) {
    gather_kernel<<<dim3((n + 3) / 4), dim3(256), 0, stream>>>(
        row_ptr, csr_src, csr_ea, Wl + l * 4 * HID, hc, agg, n);
    node_kernel<<<dim3((n + 31) / 32), dim3(256), 0, stream>>>(
        hc, agg, rel_w + l * HID * HID, rel_b + l * HID,
        root_w + l * HID * HID, res_w + l * HID * HID, hx, n);
    float* t = hc; hc = hx; hx = t;
  }

  head_kernel<<<dim3((n + 63) / 64), dim3(256), 0, stream>>>(
      hc, (const float4*)w1, (const float4*)b1, (const float4*)w2, b2,
      (float*)d_out, n);
}

// Round 7
// 579.240 us; speedup vs baseline: 1.1059x; 1.1059x over previous
//
#include <hip/hip_runtime.h>
#include <math.h>

#define HID 64
#define NLAY 5
#define NFF 512

// Broadcast lane k's value to all 64 lanes via v_readlane (k is wave-uniform).
__device__ __forceinline__ float bcastf(float v, int lane) {
  return __int_as_float(__builtin_amdgcn_readlane(__float_as_int(v), lane));
}

// Wl[l] = edge_emb_w (4x64) @ edge_lin_w[l] (64x64)  -> [4][64] per layer
__global__ void prep_wl_kernel(const float* __restrict__ edge_emb_w,
                               const float* __restrict__ edge_lin_w,
                               float* __restrict__ Wl) {
  int l = blockIdx.x;
  int t = threadIdx.x;       // 256 threads = 4 j-rows x 64 dims
  int j = t >> 6;
  int d = t & 63;
  const float* ew = edge_emb_w + j * HID;
  const float* lw = edge_lin_w + l * HID * HID;
  float acc = 0.f;
#pragma unroll
  for (int k = 0; k < HID; ++k) acc = fmaf(ew[k], lw[k * HID + d], acc);
  Wl[(l * 4 + j) * HID + d] = acc;
}

// h[n][d] = vert_emb[x[n]][d]
__global__ void embed_kernel(const int* __restrict__ x,
                             const float* __restrict__ vert_emb,
                             float* __restrict__ h, int n) {
  int idx = blockIdx.x * blockDim.x + threadIdx.x;
  if (idx >= n * HID) return;
  int node = idx >> 6;
  int d = idx & 63;
  h[idx] = vert_emb[x[node] * HID + d];
}

// ---- CSR build (once per call, reused across 5 layers) ----

__global__ void zero_deg_kernel(int* __restrict__ deg, int n) {
  int i = blockIdx.x * blockDim.x + threadIdx.x;
  if (i < n) deg[i] = 0;
}

__global__ void hist_kernel(const int* __restrict__ dst, int* __restrict__ deg, int E) {
  int e = blockIdx.x * blockDim.x + threadIdx.x;
  if (e < E) atomicAdd(&deg[dst[e]], 1);
}

// Multi-block exclusive scan, phase 1: per-block sums.
__global__ void bsum_kernel(const int* __restrict__ deg, int* __restrict__ bsum, int n) {
  __shared__ int s[256];
  int t = threadIdx.x;
  int i = blockIdx.x * 256 + t;
  s[t] = (i < n) ? deg[i] : 0;
  __syncthreads();
#pragma unroll
  for (int off = 128; off > 0; off >>= 1) {
    if (t < off) s[t] += s[t + off];
    __syncthreads();
  }
  if (t == 0) bsum[blockIdx.x] = s[0];
}

// Phase 2: one block scans the block sums -> exclusive offsets.
__global__ void bscan_kernel(const int* __restrict__ bsum, int* __restrict__ boff, int nb) {
  __shared__ int s[256];
  int t = threadIdx.x;
  int v = (t < nb) ? bsum[t] : 0;
  s[t] = v;
  __syncthreads();
#pragma unroll
  for (int off = 1; off < 256; off <<= 1) {
    int u = (t >= off) ? s[t - off] : 0;
    __syncthreads();
    s[t] += u;
    __syncthreads();
  }
  if (t < nb) boff[t] = s[t] - v;   // exclusive
}

// Phase 3: per-block scan + offset -> row_ptr, cursor; last element writes row_ptr[n].
__global__ void scan3_kernel(const int* __restrict__ deg, const int* __restrict__ boff,
                             int* __restrict__ row_ptr, int* __restrict__ cursor, int n) {
  __shared__ int s[256];
  int t = threadIdx.x;
  int i = blockIdx.x * 256 + t;
  int v = (i < n) ? deg[i] : 0;
  s[t] = v;
  __syncthreads();
#pragma unroll
  for (int off = 1; off < 256; off <<= 1) {
    int u = (t >= off) ? s[t - off] : 0;
    __syncthreads();
    s[t] += u;
    __syncthreads();
  }
  if (i < n) {
    int excl = boff[blockIdx.x] + s[t] - v;
    row_ptr[i] = excl;
    cursor[i] = excl;
    if (i == n - 1) row_ptr[n] = excl + v;
  }
}

__global__ void scatter_kernel(const int* __restrict__ src,
                               const int* __restrict__ dst,
                               const float4* __restrict__ edge_attr,
                               int* __restrict__ cursor,
                               int* __restrict__ csr_src,
                               float4* __restrict__ csr_ea, int E) {
  int e = blockIdx.x * blockDim.x + threadIdx.x;
  if (e >= E) return;
  int pos = atomicAdd(&cursor[dst[e]], 1);
  csr_src[pos] = src[e];
  csr_ea[pos] = edge_attr[e];
}

// ---- gather: 1 wave per dst node, lane = dim, 8 loads in flight ----
// __launch_bounds__(256,8): cap 64 VGPR -> 8 waves/SIMD for max latency hiding.
__global__ __launch_bounds__(256, 8)
void gather_kernel(const int* __restrict__ row_ptr,
                   const int* __restrict__ csr_src,
                   const float4* __restrict__ csr_ea,
                   const float* __restrict__ Wl,   // [4][64]
                   const float* __restrict__ h,
                   float* __restrict__ agg, int n) {
  int wid = threadIdx.x >> 6;
  int d = threadIdx.x & 63;
  int node = blockIdx.x * 4 + wid;
  if (node >= n) return;
  int beg = __builtin_amdgcn_readfirstlane(row_ptr[node]);
  int end = __builtin_amdgcn_readfirstlane(row_ptr[node + 1]);
  float w0 = Wl[d], w1_ = Wl[HID + d], w2_ = Wl[2 * HID + d], w3_ = Wl[3 * HID + d];
  float acc = 0.f;
  int j = beg;
  for (; j + 8 <= end; j += 8) {
    int s0 = csr_src[j],     s1 = csr_src[j + 1], s2 = csr_src[j + 2], s3 = csr_src[j + 3];
    int s4 = csr_src[j + 4], s5 = csr_src[j + 5], s6 = csr_src[j + 6], s7 = csr_src[j + 7];
    float h0 = h[(size_t)s0 * HID + d];
    float h1 = h[(size_t)s1 * HID + d];
    float h2 = h[(size_t)s2 * HID + d];
    float h3 = h[(size_t)s3 * HID + d];
    float h4 = h[(size_t)s4 * HID + d];
    float h5 = h[(size_t)s5 * HID + d];
    float h6 = h[(size_t)s6 * HID + d];
    float h7 = h[(size_t)s7 * HID + d];
    float4 e0 = csr_ea[j],     e1 = csr_ea[j + 1], e2 = csr_ea[j + 2], e3 = csr_ea[j + 3];
    float4 e4 = csr_ea[j + 4], e5 = csr_ea[j + 5], e6 = csr_ea[j + 6], e7 = csr_ea[j + 7];
    float v0 = fmaf(e0.w, w3_, fmaf(e0.z, w2_, fmaf(e0.y, w1_, e0.x * w0)));
    float v1 = fmaf(e1.w, w3_, fmaf(e1.z, w2_, fmaf(e1.y, w1_, e1.x * w0)));
    float v2 = fmaf(e2.w, w3_, fmaf(e2.z, w2_, fmaf(e2.y, w1_, e2.x * w0)));
    float v3 = fmaf(e3.w, w3_, fmaf(e3.z, w2_, fmaf(e3.y, w1_, e3.x * w0)));
    float v4 = fmaf(e4.w, w3_, fmaf(e4.z, w2_, fmaf(e4.y, w1_, e4.x * w0)));
    float v5 = fmaf(e5.w, w3_, fmaf(e5.z, w2_, fmaf(e5.y, w1_, e5.x * w0)));
    float v6 = fmaf(e6.w, w3_, fmaf(e6.z, w2_, fmaf(e6.y, w1_, e6.x * w0)));
    float v7 = fmaf(e7.w, w3_, fmaf(e7.z, w2_, fmaf(e7.y, w1_, e7.x * w0)));
    acc = fmaf(h0, v0, acc); acc = fmaf(h1, v1, acc);
    acc = fmaf(h2, v2, acc); acc = fmaf(h3, v3, acc);
    acc = fmaf(h4, v4, acc); acc = fmaf(h5, v5, acc);
    acc = fmaf(h6, v6, acc); acc = fmaf(h7, v7, acc);
  }
  for (; j < end; ++j) {
    int s0 = csr_src[j];
    float4 e0 = csr_ea[j];
    float v0 = fmaf(e0.w, w3_, fmaf(e0.z, w2_, fmaf(e0.y, w1_, e0.x * w0)));
    acc = fmaf(h[(size_t)s0 * HID + d], v0, acc);
  }
  agg[(size_t)node * HID + d] = acc;
}

// hn = relu(agg@rel_w + rel_b + h@root_w) + h@res_w ; 8 nodes per wave.
// Live state ~45 VGPR -> (256,8) cap of 64 is safe; 8 waves/SIMD hides weight latency.
__global__ __launch_bounds__(256, 8)
void node_kernel(const float* __restrict__ h,
                 const float* __restrict__ agg,
                 const float* __restrict__ rel_w,
                 const float* __restrict__ rel_b,
                 const float* __restrict__ root_w,
                 const float* __restrict__ res_w,
                 float* __restrict__ hn, int n) {
  int wid = threadIdx.x >> 6;
  int d = threadIdx.x & 63;
  int base = (blockIdx.x * 4 + wid) * 8;
  if (base >= n) return;
  float bd = rel_b[d];
  float hval[8], aval[8], acc2[8], accR[8];
#pragma unroll
  for (int i = 0; i < 8; ++i) {
    int node = base + i;
    bool ok = node < n;
    hval[i] = ok ? h[(size_t)node * HID + d] : 0.f;
    aval[i] = ok ? agg[(size_t)node * HID + d] : 0.f;
    acc2[i] = bd;
    accR[i] = 0.f;
  }
#pragma unroll 8
  for (int k = 0; k < HID; ++k) {
    float wr = rel_w[k * HID + d];
    float wo = root_w[k * HID + d];
    float wq = res_w[k * HID + d];
#pragma unroll
    for (int i = 0; i < 8; ++i) {
      float hk = bcastf(hval[i], k);
      float ak = bcastf(aval[i], k);
      acc2[i] = fmaf(ak, wr, acc2[i]);
      acc2[i] = fmaf(hk, wo, acc2[i]);
      accR[i] = fmaf(hk, wq, accR[i]);
    }
  }
#pragma unroll
  for (int i = 0; i < 8; ++i) {
    int node = base + i;
    if (node < n)
      hn[(size_t)node * HID + d] = fmaxf(acc2[i], 0.f) + accR[i];
  }
}

// out[n] = b2 + sum_f gelu(h[n]@w1[:,f] + b1[f]) * w2[f] ; 8 nodes per wave.
// Proven config (round 5): 104 VGPR @ (256,2), no spill, ~92 us. 16 nodes/wave
// spills (allocator caps at 128 VGPR) -- do not revisit without restructuring.
__global__ __launch_bounds__(256, 2)
void head_kernel(const float* __restrict__ h,
                 const float4* __restrict__ w1v,  // [64][128] float4
                 const float4* __restrict__ b1v,  // [128] float4
                 const float4* __restrict__ w2v,  // [128] float4
                 const float* __restrict__ b2,
                 float* __restrict__ out, int n) {
  int wid = threadIdx.x >> 6;
  int lane = threadIdx.x & 63;
  int base = (blockIdx.x * 4 + wid) * 8;
  if (base >= n) return;
  float hval[8];
#pragma unroll
  for (int i = 0; i < 8; ++i)
    hval[i] = (base + i < n) ? h[(size_t)(base + i) * HID + lane] : 0.f;
  float acc[8][8];
#pragma unroll
  for (int i = 0; i < 8; ++i)
#pragma unroll
    for (int c = 0; c < 8; ++c) acc[i][c] = 0.f;
#pragma unroll 4
  for (int k = 0; k < HID; ++k) {
    float4 wa = w1v[k * (NFF / 4) + lane * 2];
    float4 wb = w1v[k * (NFF / 4) + lane * 2 + 1];
#pragma unroll
    for (int i = 0; i < 8; ++i) {
      float hk = bcastf(hval[i], k);
      acc[i][0] = fmaf(hk, wa.x, acc[i][0]);
      acc[i][1] = fmaf(hk, wa.y, acc[i][1]);
      acc[i][2] = fmaf(hk, wa.z, acc[i][2]);
      acc[i][3] = fmaf(hk, wa.w, acc[i][3]);
      acc[i][4] = fmaf(hk, wb.x, acc[i][4]);
      acc[i][5] = fmaf(hk, wb.y, acc[i][5]);
      acc[i][6] = fmaf(hk, wb.z, acc[i][6]);
      acc[i][7] = fmaf(hk, wb.w, acc[i][7]);
    }
  }
  float4 ba = b1v[lane * 2], bb = b1v[lane * 2 + 1];
  float4 va = w2v[lane * 2], vb = w2v[lane * 2 + 1];
  float bbuf[8] = {ba.x, ba.y, ba.z, ba.w, bb.x, bb.y, bb.z, bb.w};
  float wbuf[8] = {va.x, va.y, va.z, va.w, vb.x, vb.y, vb.z, vb.w};
  float partial[8];
#pragma unroll
  for (int i = 0; i < 8; ++i) partial[i] = 0.f;
#pragma unroll
  for (int c = 0; c < 8; ++c) {
#pragma unroll
    for (int i = 0; i < 8; ++i) {
      float xv = acc[i][c] + bbuf[c];
      float g = 0.5f * xv * (1.f + erff(xv * 0.70710678118654752f)); // exact GELU
      partial[i] = fmaf(g, wbuf[c], partial[i]);
    }
  }
#pragma unroll
  for (int i = 0; i < 8; ++i) {
#pragma unroll
    for (int off = 32; off > 0; off >>= 1)
      partial[i] += __shfl_xor(partial[i], off);
  }
  if (lane == 0) {
    float bias = b2[0];
#pragma unroll
    for (int i = 0; i < 8; ++i)
      if (base + i < n) out[base + i] = partial[i] + bias;
  }
}

extern "C" void kernel_launch(void* const* d_in, const int* in_sizes, int n_in,
                              void* d_out, int out_size, void* d_ws, size_t ws_size,
                              hipStream_t stream) {
  const int*   x          = (const int*)d_in[0];
  const int*   edge_index = (const int*)d_in[1];
  const float* edge_attr  = (const float*)d_in[2];
  const float* vert_emb   = (const float*)d_in[3];
  const float* edge_emb_w = (const float*)d_in[4];
  const float* edge_lin_w = (const float*)d_in[5];
  const float* rel_w      = (const float*)d_in[6];
  const float* rel_b      = (const float*)d_in[7];
  const float* root_w     = (const float*)d_in[8];
  const float* res_w      = (const float*)d_in[9];
  const float* w1         = (const float*)d_in[10];
  const float* b1         = (const float*)d_in[11];
  const float* w2         = (const float*)d_in[12];
  const float* b2         = (const float*)d_in[13];

  const int n = in_sizes[0];
  const int E = in_sizes[2] / 4;
  const int* src = edge_index;
  const int* dst = edge_index + E;
  const int nb = (n + 255) / 256;   // scan blocks (196 for n=50000)

  // workspace layout:
  //   Wl[2048] f | hA[n*64] f | hB[n*64] f | agg[n*64] f | csr_ea[E] float4 |
  //   csr_src[E] int | row_ptr[n+1] int | cursor[n] int | deg[n] int |
  //   bsum[256] int | boff[256] int
  float* ws   = (float*)d_ws;
  float* Wl   = ws;
  float* hA   = ws + 2048;
  float* hB   = hA + (size_t)n * HID;
  float* agg  = hB + (size_t)n * HID;
  float4* csr_ea = (float4*)(agg + (size_t)n * HID);
  int* csr_src = (int*)(csr_ea + (size_t)E);
  int* row_ptr = csr_src + E;
  int* cursor  = row_ptr + (n + 1);
  int* deg     = cursor + n;
  int* bsum    = deg + n;
  int* boff    = bsum + 256;

  prep_wl_kernel<<<dim3(NLAY), dim3(256), 0, stream>>>(edge_emb_w, edge_lin_w, Wl);

  int totalHD = n * HID;
  embed_kernel<<<dim3((totalHD + 255) / 256), dim3(256), 0, stream>>>(x, vert_emb, hA, n);

  // CSR build (amortized over 5 layers)
  zero_deg_kernel<<<dim3((n + 255) / 256), dim3(256), 0, stream>>>(deg, n);
  hist_kernel<<<dim3((E + 255) / 256), dim3(256), 0, stream>>>(dst, deg, E);
  bsum_kernel<<<dim3(nb), dim3(256), 0, stream>>>(deg, bsum, n);
  bscan_kernel<<<dim3(1), dim3(256), 0, stream>>>(bsum, boff, nb);
  scan3_kernel<<<dim3(nb), dim3(256), 0, stream>>>(deg, boff, row_ptr, cursor, n);
  scatter_kernel<<<dim3((E + 255) / 256), dim3(256), 0, stream>>>(
      src, dst, (const float4*)edge_attr, cursor, csr_src, csr_ea, E);

  float* hc = hA;
  float* hx = hB;
  for (int l = 0; l < NLAY; ++l) {
    gather_kernel<<<dim3((n + 3) / 4), dim3(256), 0, stream>>>(
        row_ptr, csr_src, csr_ea, Wl + l * 4 * HID, hc, agg, n);
    node_kernel<<<dim3((n + 31) / 32), dim3(256), 0, stream>>>(
        hc, agg, rel_w + l * HID * HID, rel_b + l * HID,
        root_w + l * HID * HID, res_w + l * HID * HID, hx, n);
    float* t = hc; hc = hx; hx = t;
  }

  head_kernel<<<dim3((n + 31) / 32), dim3(256), 0, stream>>>(
      hc, (const float4*)w1, (const float4*)b1, (const float4*)w2, b2,
      (float*)d_out, n);
}